// Round 1
// baseline (68.883 us; speedup 1.0000x reference)
//
#include <hip/hip_runtime.h>

// out[b,o,c,l] = time[b,c,l] * sum_{i,k} W[o,i,c,k] * x[b,i,c,l+k-1]  (x zero-padded in l)
// b=16, i=64, c=4, L=4096, o=64, K=3

#define NB 16
#define NI 64
#define NC 4
#define NL 4096
#define NO 64
#define KW 3
#define LT 256            // l-tile per block
#define ROWS (LT + 2)     // LDS rows (l-halo of 1 each side)
#define ROWB 128          // bytes per LDS row: 64 i * 2B bf16

typedef float f32x4 __attribute__((ext_vector_type(4)));
typedef short bf16x8 __attribute__((ext_vector_type(8)));

__device__ inline unsigned short f2bf(float f) {
    unsigned int u = __builtin_bit_cast(unsigned int, f);
    u += 0x7FFFu + ((u >> 16) & 1u);          // round-to-nearest-even
    return (unsigned short)(u >> 16);
}

__global__ __launch_bounds__(256)
void tconv_mfma_kernel(const float* __restrict__ x,
                       const float* __restrict__ tt,
                       const float* __restrict__ w,
                       float* __restrict__ out)
{
    __shared__ char lds[ROWS * ROWB];         // x tile, transposed [row=l][col=i] bf16, XOR-swizzled

    const int t    = threadIdx.x;
    const int lb   = blockIdx.x * LT;
    const int c    = blockIdx.y;
    const int b    = blockIdx.z;
    const int lane = t & 63;
    const int wave = t >> 6;

    // ---------- A operand: W fragments, held in registers (one o-tile per wave) ----------
    // contraction index r = k*64 + i ; chunk cc = k*2 + ih covers i in [ih*32, ih*32+32)
    // A[m][k'] : lane holds m = lane&15 (o), k' = (lane>>4)*8 + j
    const int o0   = wave * 16;
    const int orow = o0 + (lane & 15);
    const int ksub = (lane >> 4) * 8;

    bf16x8 afrag[6];
#pragma unroll
    for (int cc = 0; cc < 6; ++cc) {
        const int k  = cc >> 1;
        const int ih = cc & 1;
        bf16x8 a;
#pragma unroll
        for (int j = 0; j < 8; ++j) {
            const int i = ih * 32 + ksub + j;
            const float wv = w[((orow * NI + i) * NC + c) * KW + k];
            a[j] = (short)f2bf(wv);
        }
        afrag[cc] = a;
    }

    // ---------- stage x tile -> LDS: transpose to [l][i], fp32->bf16, swizzle col byte ----------
    // LDS row r holds global l = lb - 1 + r
    const float* xb = x + (size_t)(b * 256 + c) * NL;   // + i*4*NL + l
#pragma unroll 4
    for (int ip = 0; ip < 32; ++ip) {
        const int i = ip * 2;
        const float* xi = xb + (size_t)i * (4 * NL);
        {
            const int r = t;
            const int l = lb - 1 + t;
            const bool ok = (l >= 0) && (l < NL);
            const float a0 = ok ? xi[l] : 0.f;
            const float a1 = ok ? xi[4 * NL + l] : 0.f;
            const unsigned int pk = (unsigned int)f2bf(a0) | ((unsigned int)f2bf(a1) << 16);
            const int off = r * ROWB + ((i * 2) ^ ((r & 7) << 4));
            *(unsigned int*)(lds + off) = pk;
        }
        if (t < 2) {                                    // straggler rows 256, 257
            const int r = 256 + t;
            const int l = lb + 255 + t;
            const bool ok = (l < NL);
            const float a0 = ok ? xi[l] : 0.f;
            const float a1 = ok ? xi[4 * NL + l] : 0.f;
            const unsigned int pk = (unsigned int)f2bf(a0) | ((unsigned int)f2bf(a1) << 16);
            const int off = r * ROWB + ((i * 2) ^ ((r & 7) << 4));
            *(unsigned int*)(lds + off) = pk;
        }
    }
    __syncthreads();

    // ---------- MFMA: 16 l-subtiles x 6 K-chunks ----------
    // B[k'][n] : lane holds k' = (lane>>4)*8 + j (8 consecutive i -> one ds_read_b128),
    //            n = lane&15 (l). LDS row = lt*16 + n + k.
    f32x4 acc[16] = {};
    const int lcol = lane & 15;

#pragma unroll
    for (int lt = 0; lt < 16; ++lt) {
#pragma unroll
        for (int cc = 0; cc < 6; ++cc) {
            const int k   = cc >> 1;
            const int ih  = cc & 1;
            const int row = lt * 16 + lcol + k;
            const int colb = ih * 64 + ksub * 2;
            const int off = row * ROWB + (colb ^ ((row & 7) << 4));
            const bf16x8 bfrag = *(const bf16x8*)(lds + off);
            acc[lt] = __builtin_amdgcn_mfma_f32_16x16x32_bf16(afrag[cc], bfrag, acc[lt], 0, 0, 0);
        }
    }

    // ---------- epilogue: multiply by time, store ----------
    // D[row][col]: o = o0 + (lane>>4)*4 + r, l = lb + lt*16 + (lane&15)
    const float* tb = tt + (size_t)(b * NC + c) * NL;
    float* ob = out + ((size_t)b * NO * NC + c) * NL;
    const int og = o0 + (lane >> 4) * 4;
#pragma unroll
    for (int lt = 0; lt < 16; ++lt) {
        const int l  = lb + lt * 16 + lcol;
        const float tv = tb[l];
#pragma unroll
        for (int r = 0; r < 4; ++r) {
            ob[(size_t)(og + r) * (NC * NL) + l] = acc[lt][r] * tv;
        }
    }
}

extern "C" void kernel_launch(void* const* d_in, const int* in_sizes, int n_in,
                              void* d_out, int out_size, void* d_ws, size_t ws_size,
                              hipStream_t stream) {
    const float* x  = (const float*)d_in[0];
    const float* tt = (const float*)d_in[1];
    const float* w  = (const float*)d_in[2];
    float* out = (float*)d_out;

    dim3 grid(NL / LT, NC, NB);   // (16, 4, 16)
    dim3 block(256);
    tconv_mfma_kernel<<<grid, block, 0, stream>>>(x, tt, w, out);
}

// Round 2
// 40.008 us; speedup vs baseline: 1.7217x; 1.7217x over previous
//
#include <hip/hip_runtime.h>

// out[b,o,c,l] = time[b,c,l] * sum_{i,k} W[o,i,c,k] * x[b,i,c,l+k-1]  (x zero-padded in l)
// b=16, i=64, c=4, L=4096, o=64, K=3
//
// Structure: per block = one (b, c, 64-wide l tile). 4 waves, each owns a
// 16-o strip. x tile staged to LDS transposed [row=l][col=i] as bf16 with
// XOR swizzle; W prepacked (kernel 1) into per-lane A-fragment order so the
// main kernel reads it with 6 coalesced 16B loads.

#define NB 16
#define NI 64
#define NC 4
#define NL 4096
#define NO 64
#define KW 3
#define LT 64             // l-tile per block
#define ROWS (LT + 2)     // LDS rows (l-halo of 1 each side)
#define ROWB 128          // bytes per LDS row: 64 i * 2B bf16

#define W_PACK_BYTES (NO * NI * NC * KW * 2)   // 98304

typedef float f32x4 __attribute__((ext_vector_type(4)));
typedef short bf16x8 __attribute__((ext_vector_type(8)));

__device__ inline unsigned short f2bf(float f) {
    unsigned int u = __builtin_bit_cast(unsigned int, f);
    u += 0x7FFFu + ((u >> 16) & 1u);          // round-to-nearest-even
    return (unsigned short)(u >> 16);
}

// ---- kernel 1: pack W into A-fragment order ----
// flat bf16 index = (((c*4 + wv)*6 + cc)*64 + lane)*8 + j
// where o = wv*16 + (lane&15), i = (cc&1)*32 + (lane>>4)*8 + j, k = cc>>1
__global__ __launch_bounds__(256)
void prepack_w_kernel(const float* __restrict__ w, unsigned short* __restrict__ wp) {
    const int idx  = blockIdx.x * 256 + threadIdx.x;     // 49152 total
    const int j    = idx & 7;
    const int lane = (idx >> 3) & 63;
    const int r9   = idx >> 9;                            // 0..95
    const int cc   = r9 % 6;
    const int wv   = (r9 / 6) & 3;
    const int c    = r9 / 24;
    const int orow = wv * 16 + (lane & 15);
    const int i    = (cc & 1) * 32 + ((lane >> 4) << 3) + j;
    const int k    = cc >> 1;
    wp[idx] = f2bf(w[((orow * NI + i) * NC + c) * KW + k]);
}

// ---- kernel 2: main ----
template <bool PREPACK>
__global__ __launch_bounds__(256)
void tconv_mfma_kernel(const float* __restrict__ x,
                       const float* __restrict__ tt,
                       const float* __restrict__ w,
                       const unsigned short* __restrict__ wp,
                       float* __restrict__ out)
{
    __shared__ char lds[ROWS * ROWB];         // x tile, [row=l][col=i] bf16, XOR-swizzled

    const int t    = threadIdx.x;
    const int lb   = blockIdx.x * LT;
    const int c    = blockIdx.y;
    const int b    = blockIdx.z;
    const int lane = t & 63;
    const int wave = t >> 6;

    // ---------- A operand: W fragments in registers (one 16-o strip per wave) ----------
    const int o0   = wave * 16;
    bf16x8 afrag[6];
    if (PREPACK) {
        const bf16x8* wpb = (const bf16x8*)wp + (size_t)((c * 4 + wave) * 6) * 64 + lane;
#pragma unroll
        for (int cc = 0; cc < 6; ++cc) afrag[cc] = wpb[cc * 64];
    } else {
        const int orow = o0 + (lane & 15);
        const int ksub = (lane >> 4) * 8;
#pragma unroll
        for (int cc = 0; cc < 6; ++cc) {
            const int k  = cc >> 1;
            const int ih = cc & 1;
            bf16x8 a;
#pragma unroll
            for (int j = 0; j < 8; ++j) {
                const int i = ih * 32 + ksub + j;
                a[j] = (short)f2bf(w[((orow * NI + i) * NC + c) * KW + k]);
            }
            afrag[cc] = a;
        }
    }

    // ---------- stage x tile -> LDS (transpose, fp32->bf16, 2 i per u32) ----------
    // LDS row r holds global l = lb - 1 + r, r in [0, 66)
    const float* xb = x + ((size_t)b * NI * NC + c) * NL;   // + i*NC*NL + l
    {
        const int rr = (t & 63) + 1;                         // rows 1..64
        const int l  = lb + (t & 63);
#pragma unroll
        for (int it = 0; it < 8; ++it) {
            const int p = it * 4 + (t >> 6);                 // i-pair 0..31
            const float* xi = xb + (size_t)(2 * p) * (NC * NL);
            const float a0 = xi[l];
            const float a1 = xi[NC * NL + l];
            const unsigned int pk = (unsigned int)f2bf(a0) | ((unsigned int)f2bf(a1) << 16);
            const int off = rr * ROWB + ((4 * p) ^ ((rr & 7) << 4));
            *(unsigned int*)(lds + off) = pk;
        }
    }
    if (t < 64) {                                            // halo rows 0 and 65
        const int p     = t >> 1;
        const int which = t & 1;
        const int r     = which ? (LT + 1) : 0;
        const int l     = which ? (lb + LT) : (lb - 1);
        const bool ok   = (l >= 0) && (l < NL);
        const float* xi = xb + (size_t)(2 * p) * (NC * NL);
        const float a0 = ok ? xi[l] : 0.f;
        const float a1 = ok ? xi[NC * NL + l] : 0.f;
        const unsigned int pk = (unsigned int)f2bf(a0) | ((unsigned int)f2bf(a1) << 16);
        const int off = r * ROWB + ((4 * p) ^ ((r & 7) << 4));
        *(unsigned int*)(lds + off) = pk;
    }
    __syncthreads();

    // ---------- MFMA: 4 l-subtiles x 6 K-chunks ----------
    f32x4 acc[LT / 16] = {};
    const int lcol = lane & 15;
    const int ksub2 = (lane >> 4) * 16;                      // byte offset of k' chunk

#pragma unroll
    for (int lt = 0; lt < LT / 16; ++lt) {
#pragma unroll
        for (int cc = 0; cc < 6; ++cc) {
            const int k    = cc >> 1;
            const int ih   = cc & 1;
            const int row  = lt * 16 + lcol + k;
            const int colb = ih * 64 + ksub2;
            const int off  = row * ROWB + (colb ^ ((row & 7) << 4));
            const bf16x8 bfrag = *(const bf16x8*)(lds + off);
            acc[lt] = __builtin_amdgcn_mfma_f32_16x16x32_bf16(afrag[cc], bfrag, acc[lt], 0, 0, 0);
        }
    }

    // ---------- epilogue: multiply by time, store ----------
    const float* tb = tt + (size_t)(b * NC + c) * NL;
    float* ob = out + ((size_t)b * NO * NC + c) * NL;
    const int og = o0 + (lane >> 4) * 4;
#pragma unroll
    for (int lt = 0; lt < LT / 16; ++lt) {
        const int l  = lb + lt * 16 + lcol;
        const float tv = tb[l];
#pragma unroll
        for (int r = 0; r < 4; ++r) {
            ob[(size_t)(og + r) * (NC * NL) + l] = acc[lt][r] * tv;
        }
    }
}

extern "C" void kernel_launch(void* const* d_in, const int* in_sizes, int n_in,
                              void* d_out, int out_size, void* d_ws, size_t ws_size,
                              hipStream_t stream) {
    const float* x  = (const float*)d_in[0];
    const float* tt = (const float*)d_in[1];
    const float* w  = (const float*)d_in[2];
    float* out = (float*)d_out;

    dim3 grid(NL / LT, NC, NB);   // (64, 4, 16) = 4096 blocks
    dim3 block(256);

    if (ws_size >= (size_t)W_PACK_BYTES) {
        unsigned short* wp = (unsigned short*)d_ws;
        prepack_w_kernel<<<dim3(NO * NI * NC * KW / 256), block, 0, stream>>>(w, wp);
        tconv_mfma_kernel<true><<<grid, block, 0, stream>>>(x, tt, w, wp, out);
    } else {
        tconv_mfma_kernel<false><<<grid, block, 0, stream>>>(x, tt, nullptr, nullptr, out);
    }
}